// Round 4
// baseline (4082.689 us; speedup 1.0000x reference)
//
#include <hip/hip_runtime.h>

// DescentPredictor: 50 SGD steps on y for E(x,y)=MLP([x;y]).
// R4: 256 blocks x 1024 threads x 64 rows. 16 waves/CU (2x occupancy vs R2),
// half the per-iter weight fetch demand (256 vs 512 block-streams). No
// launch-bounds spills (cap 128 VGPR = R2's natural allocation).

typedef unsigned short u16;
typedef u16 u16x2 __attribute__((ext_vector_type(2)));
typedef u16 u16x8 __attribute__((ext_vector_type(8)));
typedef float f32x4 __attribute__((ext_vector_type(4)));
typedef int i32x4 __attribute__((ext_vector_type(4)));
typedef __bf16 bf16x8 __attribute__((ext_vector_type(8)));

#define ITERS 50
#define EPSF 1e-5f
#define ROWS 64    // rows per block
#define STG 262    // u16 stride of staging rows (odd-dword -> bank spread)
#define AST 272    // i8 stride of A8 rows (16B-aligned MFMA frag reads)
static constexpr float SCALE = 0.1f / 16384.0f;  // LR / B

// ws byte offsets
#define OFF_W0X   0         // bf16 [256][512]
#define OFF_W0Y   262144    // i8 [256][64]
#define OFF_W0YT  278528    // i8 [64][256]
#define OFF_W1    294912    // i8 [256][256]
#define OFF_W1T   360448
#define OFF_W2    425984
#define OFF_W2T   491520
#define OFF_WSC   557056    // f32[8]: raw absmax of {W0y, W1, W2}

__device__ __forceinline__ float bf2f(u16 h) {
  union { unsigned int u; float f; } v; v.u = ((unsigned int)h) << 16; return v.f;
}
__device__ __forceinline__ u16 f2bt(float f) {  // truncating f32->bf16
  return (u16)(__builtin_bit_cast(unsigned int, f) >> 16);
}
__device__ __forceinline__ u16 f2bf(float f) {  // RNE (phase A only)
  unsigned int u = __builtin_bit_cast(unsigned int, f);
  return (u16)((u + 0x7FFFu + ((u >> 16) & 1u)) >> 16);
}
__device__ __forceinline__ float uplo(int p) {
  return __builtin_bit_cast(float, (unsigned int)p << 16);
}
__device__ __forceinline__ float uphi(int p) {
  return __builtin_bit_cast(float, (unsigned int)p & 0xffff0000u);
}
__device__ __forceinline__ int packbf2(float lo, float hi) {  // trunc pair->dword
  return __builtin_amdgcn_perm(__builtin_bit_cast(int, hi),
                               __builtin_bit_cast(int, lo), 0x07060302);
}
__device__ __forceinline__ int pack_i8x4(float a0, float a1, float a2, float a3,
                                         float qs) {
  int b0 = __float2int_rn(a0 * qs), b1 = __float2int_rn(a1 * qs);
  int b2 = __float2int_rn(a2 * qs), b3 = __float2int_rn(a3 * qs);
  int t01 = __builtin_amdgcn_perm(b1, b0, 0x00000400);
  int t23 = __builtin_amdgcn_perm(b3, b2, 0x00000400);
  return __builtin_amdgcn_perm(t23, t01, 0x05040100);
}
__device__ __forceinline__ f32x4 mfma16(u16x8 a, u16x8 b, f32x4 c) {
  return __builtin_amdgcn_mfma_f32_16x16x32_bf16(
      __builtin_bit_cast(bf16x8, a), __builtin_bit_cast(bf16x8, b), c, 0, 0, 0);
}
__device__ __forceinline__ i32x4 mfma8(i32x4 a, i32x4 b, i32x4 c) {
  return __builtin_amdgcn_mfma_i32_16x16x64_i8(a, b, c, 0, 0, 0);
}

// ---------------- prep kernels ----------------------------------------------
__global__ void prep_w0x(const float* __restrict__ W0, u16* __restrict__ dst) {
  int i = blockIdx.x * 256 + threadIdx.x;
  if (i < 131072) dst[i] = f2bf(W0[(i >> 9) * 576 + (i & 511)]);
}

__global__ void prep_init(float* sc) { if (threadIdx.x < 8) sc[threadIdx.x] = 0.f; }

__global__ void prep_absmax(const float* __restrict__ W0, const float* __restrict__ W1,
                            const float* __restrict__ W2, float* sc) {
  int i = blockIdx.x * 256 + threadIdx.x;
  float v; int slot;
  if (i < 16384)       { v = fabsf(W0[(i >> 6) * 576 + 512 + (i & 63)]); slot = 0; }
  else if (i < 81920)  { v = fabsf(W1[i - 16384]); slot = 1; }
  else                 { v = fabsf(W2[i - 81920]); slot = 2; }
#pragma unroll
  for (int m = 1; m < 64; m <<= 1) v = fmaxf(v, __shfl_xor(v, m));
  if ((threadIdx.x & 63) == 0)
    atomicMax((unsigned int*)(sc + slot), __builtin_bit_cast(unsigned int, v));
}

__global__ void prep_quant(const float* __restrict__ W0, const float* __restrict__ W1,
                           const float* __restrict__ W2, char* __restrict__ ws) {
  const float* sc = (const float*)(ws + OFF_WSC);
  int wid = blockIdx.x * 4 + (threadIdx.x >> 6);
  int lane = threadIdx.x & 63;
  if (wid < 256) {
    float qs = sc[0] > 0.f ? 127.f / sc[0] : 0.f;
    float v = W0[wid * 576 + 512 + lane];
    ws[OFF_W0Y + wid * 64 + lane] = (char)__float2int_rn(v * qs);
    return;
  }
  float v[4]; char* dst; float qs;
  if (wid < 320) {
    int r = wid - 256; qs = sc[0] > 0.f ? 127.f / sc[0] : 0.f;
#pragma unroll
    for (int e = 0; e < 4; ++e) v[e] = W0[(4 * lane + e) * 576 + 512 + r];
    dst = ws + OFF_W0YT + r * 256;
  } else if (wid < 576) {
    int r = wid - 320; qs = sc[1] > 0.f ? 127.f / sc[1] : 0.f;
#pragma unroll
    for (int e = 0; e < 4; ++e) v[e] = W1[r * 256 + 4 * lane + e];
    dst = ws + OFF_W1 + r * 256;
  } else if (wid < 832) {
    int r = wid - 576; qs = sc[1] > 0.f ? 127.f / sc[1] : 0.f;
#pragma unroll
    for (int e = 0; e < 4; ++e) v[e] = W1[(4 * lane + e) * 256 + r];
    dst = ws + OFF_W1T + r * 256;
  } else if (wid < 1088) {
    int r = wid - 832; qs = sc[2] > 0.f ? 127.f / sc[2] : 0.f;
#pragma unroll
    for (int e = 0; e < 4; ++e) v[e] = W2[r * 256 + 4 * lane + e];
    dst = ws + OFF_W2 + r * 256;
  } else {
    int r = wid - 1088; qs = sc[2] > 0.f ? 127.f / sc[2] : 0.f;
#pragma unroll
    for (int e = 0; e < 4; ++e) v[e] = W2[(4 * lane + e) * 256 + r];
    dst = ws + OFF_W2T + r * 256;
  }
  ((int*)dst)[lane] = pack_i8x4(v[0], v[1], v[2], v[3], qs);
}

// ---------------- i8 GEMM: wave = 1 Mtile (amt) x 4 Ntiles (ang) -------------
template <int KS, int LDB>
__device__ __forceinline__ void gemm8(const char* A, const char* __restrict__ Bg,
                                      i32x4 (&acc)[4], int amt, int ang,
                                      int l15, int q) {
  const char* Ab = A + (16 * amt + l15) * AST + q * 16;
  const char* Bb = Bg + (64 * ang + l15) * LDB + q * 16;
#pragma unroll
  for (int ks = 0; ks < KS; ++ks) {
    i32x4 b[4];
#pragma unroll
    for (int j = 0; j < 4; ++j) b[j] = *(const i32x4*)(Bb + 16 * j * LDB + ks * 64);
    i32x4 a = *(const i32x4*)(Ab + ks * 64);
#pragma unroll
    for (int j = 0; j < 4; ++j) acc[j] = mfma8(a, b[j], acc[j]);
  }
}

// ---------------- epilogue: dequant acc -> trunc-bf16 staging ----------------
__device__ __forceinline__ void epi_stage(u16* stg_, const i32x4 (&acc)[4],
                                          const float* rowsc, float sW,
                                          const float* bias, int amt, int ang,
                                          int l15, int q) {
  float rs[4];
#pragma unroll
  for (int rr = 0; rr < 4; ++rr) rs[rr] = rowsc[16 * amt + 4 * q + rr] * sW;
#pragma unroll
  for (int j = 0; j < 4; ++j) {
    int col = 64 * ang + 16 * j + l15;
    float b = bias ? bias[col] : 0.f;
#pragma unroll
    for (int rr = 0; rr < 4; ++rr)
      stg_[(16 * amt + 4 * q + rr) * STG + col] =
          f2bt((float)acc[j][rr] * rs[rr] + b);
  }
}

// ---------------- elementwise: 16 threads/row, thread owns cols 4cg+64k ------
__device__ __forceinline__ float ew_fwd(const u16* stg_, const float* g,
                                        const float* be, int* zq, char* A8_,
                                        float* sAArr, int t) {
  const int r = t >> 4, cg = t & 15;
  const u16* zp = stg_ + r * STG + 4 * cg;
  float z[16];
#pragma unroll
  for (int k = 0; k < 4; ++k) {
    u16x2 va = *(const u16x2*)(zp + 64 * k);
    u16x2 vb = *(const u16x2*)(zp + 64 * k + 2);
    z[4 * k] = bf2f(va[0]); z[4 * k + 1] = bf2f(va[1]);
    z[4 * k + 2] = bf2f(vb[0]); z[4 * k + 3] = bf2f(vb[1]);
  }
  float s = 0.f, ss = 0.f;
#pragma unroll
  for (int m = 0; m < 16; ++m) { s += z[m]; ss += z[m] * z[m]; }
  s += __shfl_xor(s, 1); ss += __shfl_xor(ss, 1);
  s += __shfl_xor(s, 2); ss += __shfl_xor(ss, 2);
  s += __shfl_xor(s, 4); ss += __shfl_xor(ss, 4);
  s += __shfl_xor(s, 8); ss += __shfl_xor(ss, 8);
  const float mu = s * (1.f / 256.f);
  const float var = ss * (1.f / 256.f) - mu * mu;
  const float inv = rsqrtf(var + EPSF);
  float ma = 0.f;
#pragma unroll
  for (int k = 0; k < 4; ++k) {
    int c0 = 64 * k + 4 * cg;
    f32x4 gv = *(const f32x4*)(g + c0);
    f32x4 bv = *(const f32x4*)(be + c0);
    float zn[4];
#pragma unroll
    for (int e = 0; e < 4; ++e) zn[e] = (z[4 * k + e] - mu) * inv;
    zq[2 * k] = packbf2(zn[0], zn[1]);
    zq[2 * k + 1] = packbf2(zn[2], zn[3]);
#pragma unroll
    for (int e = 0; e < 4; ++e) {
      float uu = zn[e] * gv[e] + bv[e];
      float av = uu * __builtin_amdgcn_rcpf(1.f + __expf(-uu));  // SiLU
      z[4 * k + e] = av;
      ma = fmaxf(ma, fabsf(av));
    }
  }
  ma = fmaxf(ma, __shfl_xor(ma, 1));
  ma = fmaxf(ma, __shfl_xor(ma, 2));
  ma = fmaxf(ma, __shfl_xor(ma, 4));
  ma = fmaxf(ma, __shfl_xor(ma, 8));
  float qa = ma > 0.f ? 127.f / ma : 0.f;
  if (cg == 0) sAArr[r] = ma * (1.f / 127.f);
  char* ap = A8_ + r * AST + 4 * cg;
#pragma unroll
  for (int k = 0; k < 4; ++k)
    *(int*)(ap + 64 * k) =
        pack_i8x4(z[4 * k], z[4 * k + 1], z[4 * k + 2], z[4 * k + 3], qa);
  return inv;
}

__device__ __forceinline__ void ew_l2(const u16* stg_, const float* g,
                                      const float* be, const float* wo, char* A8_,
                                      float* sAArr, int t) {
  const int r = t >> 4, cg = t & 15;
  const u16* zp = stg_ + r * STG + 4 * cg;
  float z[16];
  float s = 0.f, ss = 0.f;
#pragma unroll
  for (int k = 0; k < 4; ++k) {
    u16x2 va = *(const u16x2*)(zp + 64 * k);
    u16x2 vb = *(const u16x2*)(zp + 64 * k + 2);
    z[4 * k] = bf2f(va[0]); z[4 * k + 1] = bf2f(va[1]);
    z[4 * k + 2] = bf2f(vb[0]); z[4 * k + 3] = bf2f(vb[1]);
#pragma unroll
    for (int e = 0; e < 4; ++e) { float v = z[4 * k + e]; s += v; ss += v * v; }
  }
  s += __shfl_xor(s, 1); ss += __shfl_xor(ss, 1);
  s += __shfl_xor(s, 2); ss += __shfl_xor(ss, 2);
  s += __shfl_xor(s, 4); ss += __shfl_xor(ss, 4);
  s += __shfl_xor(s, 8); ss += __shfl_xor(ss, 8);
  const float mu = s * (1.f / 256.f);
  const float var = ss * (1.f / 256.f) - mu * mu;
  const float inv = rsqrtf(var + EPSF);
  float s1 = 0.f, s2 = 0.f;
#pragma unroll
  for (int k = 0; k < 4; ++k) {
    int c0 = 64 * k + 4 * cg;
    f32x4 gv = *(const f32x4*)(g + c0);
    f32x4 bv = *(const f32x4*)(be + c0);
    f32x4 wv = *(const f32x4*)(wo + c0);
#pragma unroll
    for (int e = 0; e < 4; ++e) {
      float zn = (z[4 * k + e] - mu) * inv;
      z[4 * k + e] = zn;
      float uu = zn * gv[e] + bv[e];
      float sg = __builtin_amdgcn_rcpf(1.f + __expf(-uu));
      float du = wv[e] * sg * (1.f + uu * (1.f - sg));
      float d = du * gv[e];
      s1 += d; s2 += d * zn;
    }
  }
  s1 += __shfl_xor(s1, 1); s2 += __shfl_xor(s2, 1);
  s1 += __shfl_xor(s1, 2); s2 += __shfl_xor(s2, 2);
  s1 += __shfl_xor(s1, 4); s2 += __shfl_xor(s2, 4);
  s1 += __shfl_xor(s1, 8); s2 += __shfl_xor(s2, 8);
  const float m1 = s1 * (1.f / 256.f), m2 = s2 * (1.f / 256.f);
  float mx = 0.f;
#pragma unroll
  for (int k = 0; k < 4; ++k) {
    int c0 = 64 * k + 4 * cg;
    f32x4 gv = *(const f32x4*)(g + c0);
    f32x4 bv = *(const f32x4*)(be + c0);
    f32x4 wv = *(const f32x4*)(wo + c0);
#pragma unroll
    for (int e = 0; e < 4; ++e) {
      float zn = z[4 * k + e];
      float uu = zn * gv[e] + bv[e];
      float sg = __builtin_amdgcn_rcpf(1.f + __expf(-uu));
      float du = wv[e] * sg * (1.f + uu * (1.f - sg));
      float dz = inv * (du * gv[e] - m1 - zn * m2);
      z[4 * k + e] = dz;
      mx = fmaxf(mx, fabsf(dz));
    }
  }
  mx = fmaxf(mx, __shfl_xor(mx, 1));
  mx = fmaxf(mx, __shfl_xor(mx, 2));
  mx = fmaxf(mx, __shfl_xor(mx, 4));
  mx = fmaxf(mx, __shfl_xor(mx, 8));
  float qd = mx > 0.f ? 127.f / mx : 0.f;
  if (cg == 0) sAArr[r] = mx * (1.f / 127.f);
  char* ap = A8_ + r * AST + 4 * cg;
#pragma unroll
  for (int k = 0; k < 4; ++k)
    *(int*)(ap + 64 * k) =
        pack_i8x4(z[4 * k], z[4 * k + 1], z[4 * k + 2], z[4 * k + 3], qd);
}

__device__ __forceinline__ void ew_bwd(const u16* stg_, const int* zq, float inv,
                                       const float* g, const float* be, char* A8_,
                                       float* sAArr, int t) {
  const int r = t >> 4, cg = t & 15;
  const u16* dp = stg_ + r * STG + 4 * cg;
  float d_[16];
  float s1 = 0.f, s2 = 0.f;
#pragma unroll
  for (int k = 0; k < 4; ++k) {
    int c0 = 64 * k + 4 * cg;
    u16x2 va = *(const u16x2*)(dp + 64 * k);
    u16x2 vb = *(const u16x2*)(dp + 64 * k + 2);
    float da[4] = {bf2f(va[0]), bf2f(va[1]), bf2f(vb[0]), bf2f(vb[1])};
    f32x4 gv = *(const f32x4*)(g + c0);
    f32x4 bv = *(const f32x4*)(be + c0);
#pragma unroll
    for (int e = 0; e < 4; ++e) {
      float zn = (e & 1) ? uphi(zq[2 * k + (e >> 1)]) : uplo(zq[2 * k + (e >> 1)]);
      float uu = zn * gv[e] + bv[e];
      float sg = __builtin_amdgcn_rcpf(1.f + __expf(-uu));
      float du = da[e] * sg * (1.f + uu * (1.f - sg));
      float dd = du * gv[e];
      d_[4 * k + e] = dd; s1 += dd; s2 += dd * zn;
    }
  }
  s1 += __shfl_xor(s1, 1); s2 += __shfl_xor(s2, 1);
  s1 += __shfl_xor(s1, 2); s2 += __shfl_xor(s2, 2);
  s1 += __shfl_xor(s1, 4); s2 += __shfl_xor(s2, 4);
  s1 += __shfl_xor(s1, 8); s2 += __shfl_xor(s2, 8);
  const float m1 = s1 * (1.f / 256.f), m2 = s2 * (1.f / 256.f);
  float mx = 0.f;
#pragma unroll
  for (int m = 0; m < 16; ++m) {
    float zn = (m & 1) ? uphi(zq[m >> 1]) : uplo(zq[m >> 1]);
    float dz = inv * (d_[m] - m1 - zn * m2);
    d_[m] = dz;
    mx = fmaxf(mx, fabsf(dz));
  }
  mx = fmaxf(mx, __shfl_xor(mx, 1));
  mx = fmaxf(mx, __shfl_xor(mx, 2));
  mx = fmaxf(mx, __shfl_xor(mx, 4));
  mx = fmaxf(mx, __shfl_xor(mx, 8));
  float qd = mx > 0.f ? 127.f / mx : 0.f;
  if (cg == 0) sAArr[r] = mx * (1.f / 127.f);
  char* ap = A8_ + r * AST + 4 * cg;
#pragma unroll
  for (int k = 0; k < 4; ++k)
    *(int*)(ap + 64 * k) =
        pack_i8x4(d_[4 * k], d_[4 * k + 1], d_[4 * k + 2], d_[4 * k + 3], qd);
}

// ---------------- main persistent kernel ------------------------------------
__global__ __launch_bounds__(1024, 4) void descent_kernel(
    const float* __restrict__ x, const float* __restrict__ y0,
    const float* __restrict__ b0, const float* __restrict__ g0, const float* __restrict__ be0,
    const float* __restrict__ b1, const float* __restrict__ g1, const float* __restrict__ be1,
    const float* __restrict__ b2, const float* __restrict__ g2, const float* __restrict__ be2,
    const float* __restrict__ wout, const char* __restrict__ ws, float* __restrict__ out) {
  __shared__ __align__(16) u16 stg[ROWS * STG];     // trunc-bf16 staging (z / da)
  __shared__ __align__(16) char A8[ROWS * AST];     // i8 act/grad GEMM-A tile
  __shared__ __align__(16) char yb[ROWS * 80];      // i8 y tile
  __shared__ __align__(16) float params[9 * 256];   // g0 be0 g1 be1 g2 be2 b1 b2 wout
  __shared__ float sA[ROWS], sY[ROWS];
  __shared__ float smax[4 * ROWS];

  const int t = threadIdx.x;
  const int w = t >> 6, lane = t & 63, l15 = lane & 15, q = lane >> 4;
  const int amt = w & 3;   // Mtile (16 rows)
  const int ang = w >> 2;  // Ngroup (4 Ntiles / 64 cols)
  const int rowbase = blockIdx.x * ROWS;

  const u16* W0X = (const u16*)(ws + OFF_W0X);
  const char* W0Yq = ws + OFF_W0Y;
  const char* W0YTq = ws + OFF_W0YT;
  const char* W1q = ws + OFF_W1;
  const char* W1Tq = ws + OFF_W1T;
  const char* W2q = ws + OFF_W2;
  const char* W2Tq = ws + OFF_W2T;
  const float* scg = (const float*)(ws + OFF_WSC);
  const float sW0Yd = scg[0] * (1.f / 127.f);
  const float sW1d = scg[1] * (1.f / 127.f);
  const float sW2d = scg[2] * (1.f / 127.f);

  if (t < 256) {
    params[0 * 256 + t] = g0[t];  params[1 * 256 + t] = be0[t];
    params[2 * 256 + t] = g1[t];  params[3 * 256 + t] = be1[t];
    params[4 * 256 + t] = g2[t];  params[5 * 256 + t] = be2[t];
    params[6 * 256 + t] = b1[t];  params[7 * 256 + t] = b2[t];
    params[8 * 256 + t] = wout[t];
  }

  // y master copy in registers (dy-GEMM C/D layout: wave = tile (amt, ang))
  float yv[4];
#pragma unroll
  for (int rr = 0; rr < 4; ++rr)
    yv[rr] = y0[(rowbase + 16 * amt + 4 * q + rr) * 64 + 16 * ang + l15];

  // Phase A: cR = x @ W0x^T + b0 (one-time bf16 MFMA), packed to bf16 pairs.
  int cRp[4][2];
  {
    const f32x4 z4 = {0.f, 0.f, 0.f, 0.f};
    f32x4 cR[4];
#pragma unroll
    for (int j = 0; j < 4; ++j) cR[j] = z4;
    const float* xp0 = x + (rowbase + 16 * amt + l15) * 512 + q * 8;
    const u16* Bb = W0X + (64 * ang + l15) * 512 + q * 8;
#pragma unroll 4
    for (int ks = 0; ks < 16; ++ks) {
      u16x8 b[4];
#pragma unroll
      for (int j = 0; j < 4; ++j) b[j] = *(const u16x8*)(Bb + 16 * j * 512 + ks * 32);
      f32x4 x0 = *(const f32x4*)(xp0 + ks * 32);
      f32x4 x1 = *(const f32x4*)(xp0 + ks * 32 + 4);
      u16x8 a;
#pragma unroll
      for (int e = 0; e < 4; ++e) { a[e] = f2bf(x0[e]); a[4 + e] = f2bf(x1[e]); }
#pragma unroll
      for (int j = 0; j < 4; ++j) cR[j] = mfma16(a, b[j], cR[j]);
    }
#pragma unroll
    for (int j = 0; j < 4; ++j) {
      float bb = b0[64 * ang + 16 * j + l15];
#pragma unroll
      for (int rr = 0; rr < 4; ++rr) cR[j][rr] += bb;
      cRp[j][0] = packbf2(cR[j][0], cR[j][1]);
      cRp[j][1] = packbf2(cR[j][2], cR[j][3]);
    }
  }
  __syncthreads();  // params ready

  int zq0[8], zq1[8];
  float inv0 = 0.f, inv1 = 0.f;

  for (int it = 0; it < ITERS; ++it) {
    // ---- y -> i8 tile with per-row scale (4 waves per row combine via smax) --
    float mx[4];
#pragma unroll
    for (int rr = 0; rr < 4; ++rr) {
      float v = fabsf(yv[rr]);
      v = fmaxf(v, __shfl_xor(v, 1));
      v = fmaxf(v, __shfl_xor(v, 2));
      v = fmaxf(v, __shfl_xor(v, 4));
      v = fmaxf(v, __shfl_xor(v, 8));
      mx[rr] = v;
    }
    if (l15 == 0)
#pragma unroll
      for (int rr = 0; rr < 4; ++rr)
        smax[ang * ROWS + 16 * amt + 4 * q + rr] = mx[rr];
    __syncthreads();  // (1)
#pragma unroll
    for (int rr = 0; rr < 4; ++rr) {
      int row = 16 * amt + 4 * q + rr;
      float m = fmaxf(fmaxf(smax[row], smax[ROWS + row]),
                      fmaxf(smax[2 * ROWS + row], smax[3 * ROWS + row]));
      float qy = m > 0.f ? 127.f / m : 0.f;
      if (ang == 0 && l15 == 0) sY[row] = m * (1.f / 127.f);
      yb[row * 80 + 16 * ang + l15] = (char)__float2int_rn(yv[rr] * qy);
    }
    __syncthreads();  // (2)

    i32x4 acc[4];
    // ---- fwd layer0: z0 = cR + y @ W0y^T ----
#pragma unroll
    for (int j = 0; j < 4; ++j) acc[j] = (i32x4){0, 0, 0, 0};
    {
      const char* Ab = yb + (16 * amt + l15) * 80 + q * 16;
      const char* Bb = W0Yq + (64 * ang + l15) * 64 + q * 16;
      i32x4 b[4];
#pragma unroll
      for (int j = 0; j < 4; ++j) b[j] = *(const i32x4*)(Bb + 16 * j * 64);
      i32x4 a = *(const i32x4*)Ab;
#pragma unroll
      for (int j = 0; j < 4; ++j) acc[j] = mfma8(a, b[j], acc[j]);
    }
    {
      float rs[4];
#pragma unroll
      for (int rr = 0; rr < 4; ++rr) rs[rr] = sY[16 * amt + 4 * q + rr] * sW0Yd;
#pragma unroll
      for (int j = 0; j < 4; ++j) {
        int col = 64 * ang + 16 * j + l15;
#pragma unroll
        for (int p = 0; p < 2; ++p) {
          float ce = uplo(cRp[j][p]), co = uphi(cRp[j][p]);
          stg[(16 * amt + 4 * q + 2 * p) * STG + col] =
              f2bt(ce + (float)acc[j][2 * p] * rs[2 * p]);
          stg[(16 * amt + 4 * q + 2 * p + 1) * STG + col] =
              f2bt(co + (float)acc[j][2 * p + 1] * rs[2 * p + 1]);
        }
      }
    }
    __syncthreads();  // (3)
    inv0 = ew_fwd(stg, &params[0 * 256], &params[1 * 256], zq0, A8, sA, t);
    __syncthreads();  // (4)

    // ---- fwd layer1 ----
#pragma unroll
    for (int j = 0; j < 4; ++j) acc[j] = (i32x4){0, 0, 0, 0};
    gemm8<4, 256>(A8, W1q, acc, amt, ang, l15, q);
    epi_stage(stg, acc, sA, sW1d, &params[6 * 256], amt, ang, l15, q);
    __syncthreads();  // (5)
    inv1 = ew_fwd(stg, &params[2 * 256], &params[3 * 256], zq1, A8, sA, t);
    __syncthreads();  // (6)

    // ---- fwd layer2 + fused top-grad + LN-bwd ----
#pragma unroll
    for (int j = 0; j < 4; ++j) acc[j] = (i32x4){0, 0, 0, 0};
    gemm8<4, 256>(A8, W2q, acc, amt, ang, l15, q);
    epi_stage(stg, acc, sA, sW2d, &params[7 * 256], amt, ang, l15, q);
    __syncthreads();  // (7)
    ew_l2(stg, &params[4 * 256], &params[5 * 256], &params[8 * 256], A8, sA, t);
    __syncthreads();  // (8)

    // ---- bwd layer2: da1 = dz2 @ W2 ----
#pragma unroll
    for (int j = 0; j < 4; ++j) acc[j] = (i32x4){0, 0, 0, 0};
    gemm8<4, 256>(A8, W2Tq, acc, amt, ang, l15, q);
    epi_stage(stg, acc, sA, sW2d, nullptr, amt, ang, l15, q);
    __syncthreads();  // (9)
    ew_bwd(stg, zq1, inv1, &params[2 * 256], &params[3 * 256], A8, sA, t);
    __syncthreads();  // (10)

    // ---- bwd layer1: da0 = dz1 @ W1 ----
#pragma unroll
    for (int j = 0; j < 4; ++j) acc[j] = (i32x4){0, 0, 0, 0};
    gemm8<4, 256>(A8, W1Tq, acc, amt, ang, l15, q);
    epi_stage(stg, acc, sA, sW1d, nullptr, amt, ang, l15, q);
    __syncthreads();  // (11)
    ew_bwd(stg, zq0, inv0, &params[0 * 256], &params[1 * 256], A8, sA, t);
    __syncthreads();  // (12)

    // ---- bwd layer0: dy = dz0 @ W0y ; y -= (LR/B)*dy ----
    i32x4 dy = {0, 0, 0, 0};
    {
      const char* Ab = A8 + (16 * amt + l15) * AST + q * 16;
      const char* B0 = W0YTq + (16 * ang + l15) * 256 + q * 16;
#pragma unroll
      for (int ks = 0; ks < 4; ++ks) {
        i32x4 a = *(const i32x4*)(Ab + ks * 64);
        dy = mfma8(a, *(const i32x4*)(B0 + ks * 64), dy);
      }
    }
    const float dsc = SCALE * sW0Yd;
#pragma unroll
    for (int rr = 0; rr < 4; ++rr)
      yv[rr] -= (float)dy[rr] * (sA[16 * amt + 4 * q + rr] * dsc);
    // loop-head barrier (1) orders next-iter smax/yb writes vs gemm_dy reads
  }

#pragma unroll
  for (int rr = 0; rr < 4; ++rr)
    out[(rowbase + 16 * amt + 4 * q + rr) * 64 + 16 * ang + l15] = yv[rr];
}

extern "C" void kernel_launch(void* const* d_in, const int* in_sizes, int n_in,
                              void* d_out, int out_size, void* d_ws, size_t ws_size,
                              hipStream_t stream) {
  const float* x   = (const float*)d_in[0];
  const float* y0  = (const float*)d_in[1];
  const float* W0  = (const float*)d_in[2];
  const float* b0  = (const float*)d_in[3];
  const float* g0  = (const float*)d_in[4];
  const float* be0 = (const float*)d_in[5];
  const float* W1  = (const float*)d_in[6];
  const float* b1  = (const float*)d_in[7];
  const float* g1  = (const float*)d_in[8];
  const float* be1 = (const float*)d_in[9];
  const float* W2  = (const float*)d_in[10];
  const float* b2  = (const float*)d_in[11];
  const float* g2  = (const float*)d_in[12];
  const float* be2 = (const float*)d_in[13];
  const float* wout = (const float*)d_in[14];
  char* ws = (char*)d_ws;  // needs 557,088 B
  float* out = (float*)d_out;

  prep_w0x<<<512, 256, 0, stream>>>(W0, (u16*)(ws + OFF_W0X));
  prep_init<<<1, 64, 0, stream>>>((float*)(ws + OFF_WSC));
  prep_absmax<<<576, 256, 0, stream>>>(W0, W1, W2, (float*)(ws + OFF_WSC));
  prep_quant<<<336, 256, 0, stream>>>(W0, W1, W2, ws);
  descent_kernel<<<256, 1024, 0, stream>>>(x, y0, b0, g0, be0, b1, g1, be1,
                                           b2, g2, be2, wout, ws, out);
}

// Round 5
// 2101.717 us; speedup vs baseline: 1.9425x; 1.9425x over previous
//
#include <hip/hip_runtime.h>

// DescentPredictor: 50 SGD steps on y for E(x,y)=MLP([x;y]).
// R5: R2 shape (512x256, no VGPR squeeze) + R3 lean EW + 8x XCD-affine weight
// replication (copy = blockIdx&7) to kill the shared-hot-set L3/fabric bottleneck.

typedef unsigned short u16;
typedef u16 u16x2 __attribute__((ext_vector_type(2)));
typedef u16 u16x8 __attribute__((ext_vector_type(8)));
typedef float f32x4 __attribute__((ext_vector_type(4)));
typedef int i32x4 __attribute__((ext_vector_type(4)));
typedef __bf16 bf16x8 __attribute__((ext_vector_type(8)));

#define ITERS 50
#define EPSF 1e-5f
#define STG 262   // u16 stride of staging rows (odd dword stride -> bank spread)
#define AST 272   // i8 stride of A8 rows (16B aligned for MFMA frag reads)
static constexpr float SCALE = 0.1f / 16384.0f;  // LR / B

// per-copy weight span (bytes) and offsets within a copy
#define CSPAN     557056
#define OFF_W0X   0         // bf16 [256][512]
#define OFF_W0Y   262144    // i8 [256][64]
#define OFF_W0YT  278528    // i8 [64][256]
#define OFF_W1    294912    // i8 [256][256]
#define OFF_W1T   360448
#define OFF_W2    425984
#define OFF_W2T   491520
#define NCOPY     8
#define OFF_WSC   (NCOPY * CSPAN)   // f32[8]: raw absmax of {W0y, W1, W2}

__device__ __forceinline__ float bf2f(u16 h) {
  union { unsigned int u; float f; } v; v.u = ((unsigned int)h) << 16; return v.f;
}
__device__ __forceinline__ u16 f2bt(float f) {  // truncating f32->bf16
  return (u16)(__builtin_bit_cast(unsigned int, f) >> 16);
}
__device__ __forceinline__ u16 f2bf(float f) {  // RNE (phase A only)
  unsigned int u = __builtin_bit_cast(unsigned int, f);
  return (u16)((u + 0x7FFFu + ((u >> 16) & 1u)) >> 16);
}
__device__ __forceinline__ float uplo(int p) {
  return __builtin_bit_cast(float, (unsigned int)p << 16);
}
__device__ __forceinline__ float uphi(int p) {
  return __builtin_bit_cast(float, (unsigned int)p & 0xffff0000u);
}
__device__ __forceinline__ int packbf2(float lo, float hi) {  // trunc pair->dword
  return __builtin_amdgcn_perm(__builtin_bit_cast(int, hi),
                               __builtin_bit_cast(int, lo), 0x07060302);
}
__device__ __forceinline__ int pack_i8x4(float a0, float a1, float a2, float a3,
                                         float qs) {
  int b0 = __float2int_rn(a0 * qs), b1 = __float2int_rn(a1 * qs);
  int b2 = __float2int_rn(a2 * qs), b3 = __float2int_rn(a3 * qs);
  int t01 = __builtin_amdgcn_perm(b1, b0, 0x00000400);
  int t23 = __builtin_amdgcn_perm(b3, b2, 0x00000400);
  return __builtin_amdgcn_perm(t23, t01, 0x05040100);
}
__device__ __forceinline__ f32x4 mfma16(u16x8 a, u16x8 b, f32x4 c) {
  return __builtin_amdgcn_mfma_f32_16x16x32_bf16(
      __builtin_bit_cast(bf16x8, a), __builtin_bit_cast(bf16x8, b), c, 0, 0, 0);
}
__device__ __forceinline__ i32x4 mfma8(i32x4 a, i32x4 b, i32x4 c) {
  return __builtin_amdgcn_mfma_i32_16x16x64_i8(a, b, c, 0, 0, 0);
}

// ---------------- prep kernels (write NCOPY copies) --------------------------
__global__ void prep_w0x(const float* __restrict__ W0, char* __restrict__ ws) {
  int i = blockIdx.x * 256 + threadIdx.x;
  u16* dst = (u16*)(ws + (size_t)blockIdx.y * CSPAN + OFF_W0X);
  if (i < 131072) dst[i] = f2bf(W0[(i >> 9) * 576 + (i & 511)]);
}

__global__ void prep_init(float* sc) { if (threadIdx.x < 8) sc[threadIdx.x] = 0.f; }

__global__ void prep_absmax(const float* __restrict__ W0, const float* __restrict__ W1,
                            const float* __restrict__ W2, float* sc) {
  int i = blockIdx.x * 256 + threadIdx.x;
  float v; int slot;
  if (i < 16384)       { v = fabsf(W0[(i >> 6) * 576 + 512 + (i & 63)]); slot = 0; }
  else if (i < 81920)  { v = fabsf(W1[i - 16384]); slot = 1; }
  else                 { v = fabsf(W2[i - 81920]); slot = 2; }
#pragma unroll
  for (int m = 1; m < 64; m <<= 1) v = fmaxf(v, __shfl_xor(v, m));
  if ((threadIdx.x & 63) == 0)
    atomicMax((unsigned int*)(sc + slot), __builtin_bit_cast(unsigned int, v));
}

__global__ void prep_quant(const float* __restrict__ W0, const float* __restrict__ W1,
                           const float* __restrict__ W2, char* __restrict__ ws) {
  const float* sc = (const float*)(ws + OFF_WSC);
  char* wsb = ws + (size_t)blockIdx.y * CSPAN;
  int wid = blockIdx.x * 4 + (threadIdx.x >> 6);
  int lane = threadIdx.x & 63;
  if (wid < 256) {
    float qs = sc[0] > 0.f ? 127.f / sc[0] : 0.f;
    float v = W0[wid * 576 + 512 + lane];
    wsb[OFF_W0Y + wid * 64 + lane] = (char)__float2int_rn(v * qs);
    return;
  }
  float v[4]; char* dst; float qs;
  if (wid < 320) {
    int r = wid - 256; qs = sc[0] > 0.f ? 127.f / sc[0] : 0.f;
#pragma unroll
    for (int e = 0; e < 4; ++e) v[e] = W0[(4 * lane + e) * 576 + 512 + r];
    dst = wsb + OFF_W0YT + r * 256;
  } else if (wid < 576) {
    int r = wid - 320; qs = sc[1] > 0.f ? 127.f / sc[1] : 0.f;
#pragma unroll
    for (int e = 0; e < 4; ++e) v[e] = W1[r * 256 + 4 * lane + e];
    dst = wsb + OFF_W1 + r * 256;
  } else if (wid < 832) {
    int r = wid - 576; qs = sc[1] > 0.f ? 127.f / sc[1] : 0.f;
#pragma unroll
    for (int e = 0; e < 4; ++e) v[e] = W1[(4 * lane + e) * 256 + r];
    dst = wsb + OFF_W1T + r * 256;
  } else if (wid < 1088) {
    int r = wid - 832; qs = sc[2] > 0.f ? 127.f / sc[2] : 0.f;
#pragma unroll
    for (int e = 0; e < 4; ++e) v[e] = W2[r * 256 + 4 * lane + e];
    dst = wsb + OFF_W2 + r * 256;
  } else {
    int r = wid - 1088; qs = sc[2] > 0.f ? 127.f / sc[2] : 0.f;
#pragma unroll
    for (int e = 0; e < 4; ++e) v[e] = W2[(4 * lane + e) * 256 + r];
    dst = wsb + OFF_W2T + r * 256;
  }
  ((int*)dst)[lane] = pack_i8x4(v[0], v[1], v[2], v[3], qs);
}

// ---------------- i8 GEMM (per-wave 2 Mtiles x 4 Ntiles, K chunks of 64) -----
template <int KS, int LDB, int ASTt>
__device__ __forceinline__ void gemm8(const char* A, const char* __restrict__ Bg,
                                      i32x4 (&acc)[2][4], int w, int l15, int q) {
  const char* Ab = A + l15 * ASTt + q * 16;
  const char* Bb = Bg + (64 * w + l15) * LDB + q * 16;
#pragma unroll
  for (int ks = 0; ks < KS; ++ks) {
    i32x4 b[4];
#pragma unroll
    for (int j = 0; j < 4; ++j) b[j] = *(const i32x4*)(Bb + 16 * j * LDB + ks * 64);
#pragma unroll
    for (int i = 0; i < 2; ++i) {
      i32x4 a = *(const i32x4*)(Ab + 16 * i * ASTt + ks * 64);
#pragma unroll
      for (int j = 0; j < 4; ++j) acc[i][j] = mfma8(a, b[j], acc[i][j]);
    }
  }
}

__device__ __forceinline__ void gemm_dy8(const char* A, const char* __restrict__ BT,
                                         i32x4 (&dy)[2], int mi, int nb, int l15, int q) {
  const char* Ab = A + (mi * 16 + l15) * AST + q * 16;
  const char* B0 = BT + (nb + l15) * 256 + q * 16;
  const char* B1 = BT + (nb + 16 + l15) * 256 + q * 16;
#pragma unroll
  for (int ks = 0; ks < 4; ++ks) {
    i32x4 a = *(const i32x4*)(Ab + ks * 64);
    dy[0] = mfma8(a, *(const i32x4*)(B0 + ks * 64), dy[0]);
    dy[1] = mfma8(a, *(const i32x4*)(B1 + ks * 64), dy[1]);
  }
}

// ---------------- epilogue: dequant acc -> trunc-bf16 staging ---------------
__device__ __forceinline__ void epi_stage(u16* stg, const i32x4 (&acc)[2][4],
                                          const float* rowsc, float sW,
                                          const float* bias, int w, int l15, int q) {
#pragma unroll
  for (int i = 0; i < 2; ++i) {
    float rs[4];
#pragma unroll
    for (int rr = 0; rr < 4; ++rr) rs[rr] = rowsc[16 * i + 4 * q + rr] * sW;
#pragma unroll
    for (int j = 0; j < 4; ++j) {
      int col = 64 * w + 16 * j + l15;
      float b = bias ? bias[col] : 0.f;
#pragma unroll
      for (int rr = 0; rr < 4; ++rr)
        stg[(16 * i + 4 * q + rr) * STG + col] =
            f2bt((float)acc[i][j][rr] * rs[rr] + b);
    }
  }
}

// ---------------- elementwise (thread = (row r, col-group cg); cols 4cg+32k) -
__device__ __forceinline__ float ew_fwd(const u16* stg_, const float* g,
                                        const float* be, int* zq, char* A8_,
                                        float* sAArr, int t) {
  const int r = t >> 3, cg = t & 7;
  const u16* zp = stg_ + r * STG;
  float z[32];
#pragma unroll
  for (int k = 0; k < 8; ++k) {
    int c0 = 32 * k + 4 * cg;
    u16x2 va = *(const u16x2*)(zp + c0);
    u16x2 vb = *(const u16x2*)(zp + c0 + 2);
    z[4 * k] = bf2f(va[0]); z[4 * k + 1] = bf2f(va[1]);
    z[4 * k + 2] = bf2f(vb[0]); z[4 * k + 3] = bf2f(vb[1]);
  }
  float s = 0.f, ss = 0.f;
#pragma unroll
  for (int m = 0; m < 32; ++m) { s += z[m]; ss += z[m] * z[m]; }
  s += __shfl_xor(s, 1); ss += __shfl_xor(ss, 1);
  s += __shfl_xor(s, 2); ss += __shfl_xor(ss, 2);
  s += __shfl_xor(s, 4); ss += __shfl_xor(ss, 4);
  const float mu = s * (1.f / 256.f);
  const float var = ss * (1.f / 256.f) - mu * mu;
  const float inv = rsqrtf(var + EPSF);
  float ma = 0.f;
#pragma unroll
  for (int k = 0; k < 8; ++k) {
    int c0 = 32 * k + 4 * cg;
    f32x4 gv = *(const f32x4*)(g + c0);
    f32x4 bv = *(const f32x4*)(be + c0);
    float zn[4];
#pragma unroll
    for (int e = 0; e < 4; ++e) zn[e] = (z[4 * k + e] - mu) * inv;
    zq[2 * k] = packbf2(zn[0], zn[1]);
    zq[2 * k + 1] = packbf2(zn[2], zn[3]);
#pragma unroll
    for (int e = 0; e < 4; ++e) {
      float uu = zn[e] * gv[e] + bv[e];
      float av = uu * __builtin_amdgcn_rcpf(1.f + __expf(-uu));  // SiLU
      z[4 * k + e] = av;
      ma = fmaxf(ma, fabsf(av));
    }
  }
  ma = fmaxf(ma, __shfl_xor(ma, 1));
  ma = fmaxf(ma, __shfl_xor(ma, 2));
  ma = fmaxf(ma, __shfl_xor(ma, 4));
  float qa = ma > 0.f ? 127.f / ma : 0.f;
  if (cg == 0) sAArr[r] = ma * (1.f / 127.f);
  char* ap = A8_ + r * AST;
#pragma unroll
  for (int k = 0; k < 8; ++k)
    *(int*)(ap + 32 * k + 4 * cg) =
        pack_i8x4(z[4 * k], z[4 * k + 1], z[4 * k + 2], z[4 * k + 3], qa);
  return inv;
}

__device__ __forceinline__ void ew_l2(const u16* stg_, const float* g,
                                      const float* be, const float* wo, char* A8_,
                                      float* sAArr, int t) {
  const int r = t >> 3, cg = t & 7;
  const u16* zp = stg_ + r * STG;
  float z[32];
  float s = 0.f, ss = 0.f;
#pragma unroll
  for (int k = 0; k < 8; ++k) {
    int c0 = 32 * k + 4 * cg;
    u16x2 va = *(const u16x2*)(zp + c0);
    u16x2 vb = *(const u16x2*)(zp + c0 + 2);
    z[4 * k] = bf2f(va[0]); z[4 * k + 1] = bf2f(va[1]);
    z[4 * k + 2] = bf2f(vb[0]); z[4 * k + 3] = bf2f(vb[1]);
#pragma unroll
    for (int e = 0; e < 4; ++e) { float v = z[4 * k + e]; s += v; ss += v * v; }
  }
  s += __shfl_xor(s, 1); ss += __shfl_xor(ss, 1);
  s += __shfl_xor(s, 2); ss += __shfl_xor(ss, 2);
  s += __shfl_xor(s, 4); ss += __shfl_xor(ss, 4);
  const float mu = s * (1.f / 256.f);
  const float var = ss * (1.f / 256.f) - mu * mu;
  const float inv = rsqrtf(var + EPSF);
  float s1 = 0.f, s2 = 0.f;
#pragma unroll
  for (int k = 0; k < 8; ++k) {
    int c0 = 32 * k + 4 * cg;
    f32x4 gv = *(const f32x4*)(g + c0);
    f32x4 bv = *(const f32x4*)(be + c0);
    f32x4 wv = *(const f32x4*)(wo + c0);
#pragma unroll
    for (int e = 0; e < 4; ++e) {
      float zn = (z[4 * k + e] - mu) * inv;
      z[4 * k + e] = zn;
      float uu = zn * gv[e] + bv[e];
      float sg = __builtin_amdgcn_rcpf(1.f + __expf(-uu));
      float du = wv[e] * sg * (1.f + uu * (1.f - sg));
      float d = du * gv[e];
      s1 += d; s2 += d * zn;
    }
  }
  s1 += __shfl_xor(s1, 1); s2 += __shfl_xor(s2, 1);
  s1 += __shfl_xor(s1, 2); s2 += __shfl_xor(s2, 2);
  s1 += __shfl_xor(s1, 4); s2 += __shfl_xor(s2, 4);
  const float m1 = s1 * (1.f / 256.f), m2 = s2 * (1.f / 256.f);
  float mx = 0.f;
#pragma unroll
  for (int k = 0; k < 8; ++k) {
    int c0 = 32 * k + 4 * cg;
    f32x4 gv = *(const f32x4*)(g + c0);
    f32x4 bv = *(const f32x4*)(be + c0);
    f32x4 wv = *(const f32x4*)(wo + c0);
#pragma unroll
    for (int e = 0; e < 4; ++e) {
      float zn = z[4 * k + e];
      float uu = zn * gv[e] + bv[e];
      float sg = __builtin_amdgcn_rcpf(1.f + __expf(-uu));
      float du = wv[e] * sg * (1.f + uu * (1.f - sg));
      float dz = inv * (du * gv[e] - m1 - zn * m2);
      z[4 * k + e] = dz;
      mx = fmaxf(mx, fabsf(dz));
    }
  }
  mx = fmaxf(mx, __shfl_xor(mx, 1));
  mx = fmaxf(mx, __shfl_xor(mx, 2));
  mx = fmaxf(mx, __shfl_xor(mx, 4));
  float qd = mx > 0.f ? 127.f / mx : 0.f;
  if (cg == 0) sAArr[r] = mx * (1.f / 127.f);
  char* ap = A8_ + r * AST;
#pragma unroll
  for (int k = 0; k < 8; ++k)
    *(int*)(ap + 32 * k + 4 * cg) =
        pack_i8x4(z[4 * k], z[4 * k + 1], z[4 * k + 2], z[4 * k + 3], qd);
}

__device__ __forceinline__ void ew_bwd(const u16* stg_, const int* zq, float inv,
                                       const float* g, const float* be, char* A8_,
                                       float* sAArr, int t) {
  const int r = t >> 3, cg = t & 7;
  const u16* dp = stg_ + r * STG;
  float d_[32];
  float s1 = 0.f, s2 = 0.f;
#pragma unroll
  for (int k = 0; k < 8; ++k) {
    int c0 = 32 * k + 4 * cg;
    u16x2 va = *(const u16x2*)(dp + c0);
    u16x2 vb = *(const u16x2*)(dp + c0 + 2);
    float da[4] = {bf2f(va[0]), bf2f(va[1]), bf2f(vb[0]), bf2f(vb[1])};
    f32x4 gv = *(const f32x4*)(g + c0);
    f32x4 bv = *(const f32x4*)(be + c0);
#pragma unroll
    for (int e = 0; e < 4; ++e) {
      float zn = (e & 1) ? uphi(zq[2 * k + (e >> 1)]) : uplo(zq[2 * k + (e >> 1)]);
      float uu = zn * gv[e] + bv[e];
      float sg = __builtin_amdgcn_rcpf(1.f + __expf(-uu));
      float du = da[e] * sg * (1.f + uu * (1.f - sg));
      float dd = du * gv[e];
      d_[4 * k + e] = dd; s1 += dd; s2 += dd * zn;
    }
  }
  s1 += __shfl_xor(s1, 1); s2 += __shfl_xor(s2, 1);
  s1 += __shfl_xor(s1, 2); s2 += __shfl_xor(s2, 2);
  s1 += __shfl_xor(s1, 4); s2 += __shfl_xor(s2, 4);
  const float m1 = s1 * (1.f / 256.f), m2 = s2 * (1.f / 256.f);
  float mx = 0.f;
#pragma unroll
  for (int m = 0; m < 32; ++m) {
    float zn = (m & 1) ? uphi(zq[m >> 1]) : uplo(zq[m >> 1]);
    float dz = inv * (d_[m] - m1 - zn * m2);
    d_[m] = dz;
    mx = fmaxf(mx, fabsf(dz));
  }
  mx = fmaxf(mx, __shfl_xor(mx, 1));
  mx = fmaxf(mx, __shfl_xor(mx, 2));
  mx = fmaxf(mx, __shfl_xor(mx, 4));
  float qd = mx > 0.f ? 127.f / mx : 0.f;
  if (cg == 0) sAArr[r] = mx * (1.f / 127.f);
  char* ap = A8_ + r * AST;
#pragma unroll
  for (int k = 0; k < 8; ++k)
    *(int*)(ap + 32 * k + 4 * cg) =
        pack_i8x4(d_[4 * k], d_[4 * k + 1], d_[4 * k + 2], d_[4 * k + 3], qd);
}

// ---------------- main persistent kernel ------------------------------------
__global__ __launch_bounds__(256, 2) void descent_kernel(
    const float* __restrict__ x, const float* __restrict__ y0,
    const float* __restrict__ b0, const float* __restrict__ g0, const float* __restrict__ be0,
    const float* __restrict__ b1, const float* __restrict__ g1, const float* __restrict__ be1,
    const float* __restrict__ b2, const float* __restrict__ g2, const float* __restrict__ be2,
    const float* __restrict__ wout, const char* __restrict__ ws, float* __restrict__ out) {
  __shared__ __align__(16) u16 stg[32 * STG];     // trunc-bf16 staging (z / da)
  __shared__ __align__(16) char A8[32 * AST];     // i8 act/grad GEMM-A tile
  __shared__ __align__(16) char yb[32 * 80];      // i8 y tile
  __shared__ __align__(16) float params[9 * 256]; // g0 be0 g1 be1 g2 be2 b1 b2 wout
  __shared__ float sA[32], sY[32];
  __shared__ float smax[64];

  const int t = threadIdx.x;
  const int w = t >> 6, lane = t & 63, l15 = lane & 15, q = lane >> 4;
  const int rowbase = blockIdx.x * 32;

  // XCD-affine weight copy (round-robin dispatch heuristic; perf-only)
  const char* wsb = ws + (size_t)(blockIdx.x & (NCOPY - 1)) * CSPAN;
  const u16* W0X = (const u16*)(wsb + OFF_W0X);
  const char* W0Yq = wsb + OFF_W0Y;
  const char* W0YTq = wsb + OFF_W0YT;
  const char* W1q = wsb + OFF_W1;
  const char* W1Tq = wsb + OFF_W1T;
  const char* W2q = wsb + OFF_W2;
  const char* W2Tq = wsb + OFF_W2T;
  const float* scg = (const float*)(ws + OFF_WSC);
  const float sW0Yd = scg[0] * (1.f / 127.f);
  const float sW1d = scg[1] * (1.f / 127.f);
  const float sW2d = scg[2] * (1.f / 127.f);

  params[0 * 256 + t] = g0[t];  params[1 * 256 + t] = be0[t];
  params[2 * 256 + t] = g1[t];  params[3 * 256 + t] = be1[t];
  params[4 * 256 + t] = g2[t];  params[5 * 256 + t] = be2[t];
  params[6 * 256 + t] = b1[t];  params[7 * 256 + t] = b2[t];
  params[8 * 256 + t] = wout[t];

  // y master copy in registers (gemm_dy C/D layout)
  const int mi = w >> 1, nb = (w & 1) * 32;
  float yv[2][4];
#pragma unroll
  for (int j = 0; j < 2; ++j)
#pragma unroll
    for (int rr = 0; rr < 4; ++rr)
      yv[j][rr] = y0[(rowbase + mi * 16 + q * 4 + rr) * 64 + nb + 16 * j + l15];

  const f32x4 z4 = {0.f, 0.f, 0.f, 0.f};

  // Phase A: cR = x @ W0x^T + b0 (one-time bf16 MFMA), then packed to bf16.
  int cRp[2][4][2];
  {
    f32x4 cR[2][4];
#pragma unroll
    for (int i = 0; i < 2; ++i)
#pragma unroll
      for (int j = 0; j < 4; ++j) cR[i][j] = z4;
    const float* xp0 = x + (rowbase + l15) * 512 + q * 8;
    const u16* Bb = W0X + (64 * w + l15) * 512 + q * 8;
#pragma unroll 4
    for (int ks = 0; ks < 16; ++ks) {
      u16x8 b[4];
#pragma unroll
      for (int j = 0; j < 4; ++j) b[j] = *(const u16x8*)(Bb + 16 * j * 512 + ks * 32);
#pragma unroll
      for (int i = 0; i < 2; ++i) {
        const float* xp = xp0 + i * 16 * 512 + ks * 32;
        f32x4 x0 = *(const f32x4*)xp;
        f32x4 x1 = *(const f32x4*)(xp + 4);
        u16x8 a;
#pragma unroll
        for (int e = 0; e < 4; ++e) { a[e] = f2bf(x0[e]); a[4 + e] = f2bf(x1[e]); }
#pragma unroll
        for (int j = 0; j < 4; ++j) cR[i][j] = mfma16(a, b[j], cR[i][j]);
      }
    }
#pragma unroll
    for (int j = 0; j < 4; ++j) {
      float bb = b0[64 * w + 16 * j + l15];
#pragma unroll
      for (int i = 0; i < 2; ++i) {
#pragma unroll
        for (int rr = 0; rr < 4; ++rr) cR[i][j][rr] += bb;
        cRp[i][j][0] = packbf2(cR[i][j][0], cR[i][j][1]);
        cRp[i][j][1] = packbf2(cR[i][j][2], cR[i][j][3]);
      }
    }
  }
  __syncthreads();  // params ready

  int zq0[16], zq1[16];
  float inv0 = 0.f, inv1 = 0.f;

  for (int it = 0; it < ITERS; ++it) {
    // ---- y -> i8 tile with per-row scale ----
    float mx[4];
#pragma unroll
    for (int rr = 0; rr < 4; ++rr)
      mx[rr] = fmaxf(fabsf(yv[0][rr]), fabsf(yv[1][rr]));
#pragma unroll
    for (int m = 1; m < 16; m <<= 1)
#pragma unroll
      for (int rr = 0; rr < 4; ++rr) mx[rr] = fmaxf(mx[rr], __shfl_xor(mx[rr], m));
    if (l15 == 0)
#pragma unroll
      for (int rr = 0; rr < 4; ++rr) smax[w * 16 + q * 4 + rr] = mx[rr];
    __syncthreads();  // (1)
#pragma unroll
    for (int rr = 0; rr < 4; ++rr) {
      float m2 = fmaxf(mx[rr], smax[(w ^ 1) * 16 + q * 4 + rr]);
      float qy = m2 > 0.f ? 127.f / m2 : 0.f;
      int row = 16 * mi + 4 * q + rr;
      if (l15 == 0 && (w & 1) == 0) sY[row] = m2 * (1.f / 127.f);
#pragma unroll
      for (int j = 0; j < 2; ++j)
        yb[row * 80 + nb + 16 * j + l15] = (char)__float2int_rn(yv[j][rr] * qy);
    }
    __syncthreads();  // (2)

    i32x4 acc[2][4];
    // ---- fwd layer0: z0 = cR + y @ W0y^T ----
#pragma unroll
    for (int i = 0; i < 2; ++i)
#pragma unroll
      for (int j = 0; j < 4; ++j) acc[i][j] = (i32x4){0, 0, 0, 0};
    gemm8<1, 64, 80>(yb, W0Yq, acc, w, l15, q);
#pragma unroll
    for (int i = 0; i < 2; ++i) {
      float rs[4];
#pragma unroll
      for (int rr = 0; rr < 4; ++rr) rs[rr] = sY[16 * i + 4 * q + rr] * sW0Yd;
#pragma unroll
      for (int j = 0; j < 4; ++j) {
        int col = 64 * w + 16 * j + l15;
#pragma unroll
        for (int p = 0; p < 2; ++p) {
          float ce = uplo(cRp[i][j][p]), co = uphi(cRp[i][j][p]);
          stg[(16 * i + 4 * q + 2 * p) * STG + col] =
              f2bt(ce + (float)acc[i][j][2 * p] * rs[2 * p]);
          stg[(16 * i + 4 * q + 2 * p + 1) * STG + col] =
              f2bt(co + (float)acc[i][j][2 * p + 1] * rs[2 * p + 1]);
        }
      }
    }
    __syncthreads();  // (3)
    inv0 = ew_fwd(stg, &params[0 * 256], &params[1 * 256], zq0, A8, sA, t);
    __syncthreads();  // (4)

    // ---- fwd layer1 ----
#pragma unroll
    for (int i = 0; i < 2; ++i)
#pragma unroll
      for (int j = 0; j < 4; ++j) acc[i][j] = (i32x4){0, 0, 0, 0};
    gemm8<4, 256, AST>(A8, W1q, acc, w, l15, q);
    epi_stage(stg, acc, sA, sW1d, &params[6 * 256], w, l15, q);
    __syncthreads();  // (5)
    inv1 = ew_fwd(stg, &params[2 * 256], &params[3 * 256], zq1, A8, sA, t);
    __syncthreads();  // (6)

    // ---- fwd layer2 + fused top-grad + LN-bwd ----
#pragma unroll
    for (int i = 0; i < 2; ++i)
#pragma unroll
      for (int j = 0; j < 4; ++j) acc[i][j] = (i32x4){0, 0, 0, 0};
    gemm8<4, 256, AST>(A8, W2q, acc, w, l15, q);
    epi_stage(stg, acc, sA, sW2d, &params[7 * 256], w, l15, q);
    __syncthreads();  // (7)
    ew_l2(stg, &params[4 * 256], &params[5 * 256], &params[8 * 256], A8, sA, t);
    __syncthreads();  // (8)

    // ---- bwd layer2: da1 = dz2 @ W2 ----
#pragma unroll
    for (int i = 0; i < 2; ++i)
#pragma unroll
      for (int j = 0; j < 4; ++j) acc[i][j] = (i32x4){0, 0, 0, 0};
    gemm8<4, 256, AST>(A8, W2Tq, acc, w, l15, q);
    epi_stage(stg, acc, sA, sW2d, nullptr, w, l15, q);
    __syncthreads();  // (9)
    ew_bwd(stg, zq1, inv1, &params[2 * 256], &params[3 * 256], A8, sA, t);
    __syncthreads();  // (10)

    // ---- bwd layer1: da0 = dz1 @ W1 ----
#pragma unroll
    for (int i = 0; i < 2; ++i)
#pragma unroll
      for (int j = 0; j < 4; ++j) acc[i][j] = (i32x4){0, 0, 0, 0};
    gemm8<4, 256, AST>(A8, W1Tq, acc, w, l15, q);
    epi_stage(stg, acc, sA, sW1d, nullptr, w, l15, q);
    __syncthreads();  // (11)
    ew_bwd(stg, zq0, inv0, &params[0 * 256], &params[1 * 256], A8, sA, t);
    __syncthreads();  // (12)

    // ---- bwd layer0: dy = dz0 @ W0y ; y -= (LR/B)*dy ----
    i32x4 dy[2] = {{0, 0, 0, 0}, {0, 0, 0, 0}};
    gemm_dy8(A8, W0YTq, dy, mi, nb, l15, q);
    const float dsc = SCALE * sW0Yd;
#pragma unroll
    for (int rr = 0; rr < 4; ++rr) {
      float rsc = sA[16 * mi + 4 * q + rr] * dsc;
#pragma unroll
      for (int j = 0; j < 2; ++j) yv[j][rr] -= (float)dy[j][rr] * rsc;
    }
    // loop-head barrier (1) orders next-iter smax/yb writes vs gemm_dy reads
  }

#pragma unroll
  for (int j = 0; j < 2; ++j)
#pragma unroll
    for (int rr = 0; rr < 4; ++rr)
      out[(rowbase + mi * 16 + q * 4 + rr) * 64 + nb + 16 * j + l15] = yv[j][rr];
}

extern "C" void kernel_launch(void* const* d_in, const int* in_sizes, int n_in,
                              void* d_out, int out_size, void* d_ws, size_t ws_size,
                              hipStream_t stream) {
  const float* x   = (const float*)d_in[0];
  const float* y0  = (const float*)d_in[1];
  const float* W0  = (const float*)d_in[2];
  const float* b0  = (const float*)d_in[3];
  const float* g0  = (const float*)d_in[4];
  const float* be0 = (const float*)d_in[5];
  const float* W1  = (const float*)d_in[6];
  const float* b1  = (const float*)d_in[7];
  const float* g1  = (const float*)d_in[8];
  const float* be1 = (const float*)d_in[9];
  const float* W2  = (const float*)d_in[10];
  const float* b2  = (const float*)d_in[11];
  const float* g2  = (const float*)d_in[12];
  const float* be2 = (const float*)d_in[13];
  const float* wout = (const float*)d_in[14];
  char* ws = (char*)d_ws;  // needs NCOPY*CSPAN + 32 = 4,456,480 B
  float* out = (float*)d_out;

  prep_init<<<1, 64, 0, stream>>>((float*)(ws + OFF_WSC));
  prep_absmax<<<576, 256, 0, stream>>>(W0, W1, W2, (float*)(ws + OFF_WSC));
  prep_w0x<<<dim3(512, NCOPY), 256, 0, stream>>>(W0, ws);
  prep_quant<<<dim3(336, NCOPY), 256, 0, stream>>>(W0, W1, W2, ws);
  descent_kernel<<<512, 256, 0, stream>>>(x, y0, b0, g0, be0, b1, g1, be1,
                                          b2, g2, be2, wout, ws, out);
}